// Round 7
// baseline (86.446 us; speedup 1.0000x reference)
//
#include <hip/hip_runtime.h>
#include <hip/hip_bf16.h>

// SeqChamferLoss: B=4, C=3, T=16, N=2048, fp32 in, scalar fp32 out.
// loss = mean over (b,t) of [ sum_m min_n d2 + sum_n min_m d2 ], x=gts, y=preds.
//
// R6 (resubmit after infra timeout): R5 structure (1024 blocks, 32KB LDS,
// 4 blocks/CU, exact bf16-split MFMA) plus latency attacks:
//  - explicit next-tile prefetch (ds_read decoupled from current tile's fold)
//  - staggered MFMA/fold (fold d[j] after issuing MFMA j+1)
//  - balanced depth-3 min3 tree (8 ops)
//  - finishA+finishB merged (atomicAdd), out zeroed via 4B memset

typedef short short8 __attribute__((ext_vector_type(8)));
typedef float f32x16 __attribute__((ext_vector_type(16)));

#define BV 4
#define CV 3
#define TV 16
#define NV 2048
#define PS (TV * NV)
#define THREADS 256
#define NT 32            // ref tiles per block (half of 2048/32)
#define MPW 4            // query (m) tiles per wave
#define NBLK 1024        // sl(64) x dir(2) x q(4) x rhalf(2)

static __device__ inline short bfh(float v) {
    __hip_bfloat16 h = __float2bfloat16(v);
    return *reinterpret_cast<short*>(&h);
}
static __device__ inline float bff(short s) {
    __hip_bfloat16 h;
    *reinterpret_cast<short*>(&h) = s;
    return __bfloat162float(h);
}
static __device__ inline void split2(float v, short& hi, short& lo) {
    short h = bfh(v);
    hi = h;
    lo = bfh(v - bff(h));
}
static __device__ inline float min3(float a, float b, float c) {
    return fminf(fminf(a, b), c);
}
// balanced fold of 16 MFMA results + carry, 8 min3 ops, depth 3
static __device__ inline float fold16(float accv, const f32x16& d) {
    float t0 = min3(d[0], d[1], d[2]);
    float t1 = min3(d[3], d[4], d[5]);
    float t2 = min3(d[6], d[7], d[8]);
    float t3 = min3(d[9], d[10], d[11]);
    float t4 = min3(d[12], d[13], d[14]);
    float u0 = min3(t0, t1, d[15]);
    float u1 = min3(t2, t3, t4);
    return min3(accv, u0, u1);
}

__global__ __launch_bounds__(THREADS, 4)
void chamfer_kernel(const float* __restrict__ preds,
                    const float* __restrict__ gts,
                    float* __restrict__ pmin)
{
    __shared__ short8 afr[NT * 64];          // 32 KB

    const int tid  = threadIdx.x;
    const int lane = tid & 63;
    const int wid  = tid >> 6;
    const int col  = lane & 31;
    const int half = lane >> 5;

    const int blk = blockIdx.x;              // ((sl*2+dir)*4+q)*2 + rh
    const int rh  = blk & 1;
    const int q   = (blk >> 1) & 3;
    const int dir = (blk >> 3) & 1;
    const int sl  = blk >> 4;
    const int b   = sl >> 4, t = sl & 15;

    const size_t base = ((size_t)b * CV * TV + t) * NV;
    const float* rsrc = (dir ? preds : gts) + base;   // refs
    const float* qsrc = (dir ? gts : preds) + base;   // queries

    // ---- A-side (ref) fragments into LDS ----
    // K pattern A: [sh0,sh1,sh2,sh0,sh1,sh2,sl0,sl1 | sl2,sl0,sl1,sl2,rxh,rxl,0,0]
    // K pattern B: [yh0,yh1,yh2,yl0,yl1,yl2,yh0,yh1 | yh2,yl0,yl1,yl2, 1 , 1 ,0,0]
#pragma unroll
    for (int i = 0; i < 4; ++i) {
        int p  = tid + THREADS * i;
        int rp = rh * 1024 + p;
        float x0 = rsrc[rp], x1 = rsrc[PS + rp], x2 = rsrc[2 * PS + rp];
        float rx = fmaf(x0, x0, fmaf(x1, x1, x2 * x2));
        short sh0, sl0, sh1, sl1, sh2, sl2, rxh, rxl;
        split2(-2.f * x0, sh0, sl0);
        split2(-2.f * x1, sh1, sl1);
        split2(-2.f * x2, sh2, sl2);
        split2(rx, rxh, rxl);
        short8 h0, h1;
        h0[0] = sh0; h0[1] = sh1; h0[2] = sh2; h0[3] = sh0;
        h0[4] = sh1; h0[5] = sh2; h0[6] = sl0; h0[7] = sl1;
        h1[0] = sl2; h1[1] = sl0; h1[2] = sl1; h1[3] = sl2;
        h1[4] = rxh; h1[5] = rxl; h1[6] = 0;   h1[7] = 0;
        int slot = (p >> 5) * 64 + (p & 31);
        afr[slot]      = h0;
        afr[slot + 32] = h1;
    }

    // ---- B-side (query) fragments in registers ----
    short8 bfr[MPW];
    float  ry[MPW];
    const short ONE = 0x3F80;
#pragma unroll
    for (int j = 0; j < MPW; ++j) {
        int mt = q * 16 + wid * 4 + j;
        int m  = mt * 32 + col;
        float y0 = qsrc[m], y1 = qsrc[PS + m], y2 = qsrc[2 * PS + m];
        ry[j] = fmaf(y0, y0, fmaf(y1, y1, y2 * y2));
        short yh0, yl0, yh1, yl1, yh2, yl2;
        split2(y0, yh0, yl0);
        split2(y1, yh1, yl1);
        split2(y2, yh2, yl2);
        short8 f;
        if (half == 0) {
            f[0] = yh0; f[1] = yh1; f[2] = yh2; f[3] = yl0;
            f[4] = yl1; f[5] = yl2; f[6] = yh0; f[7] = yh1;
        } else {
            f[0] = yh2; f[1] = yl0; f[2] = yl1; f[3] = yl2;
            f[4] = ONE; f[5] = ONE; f[6] = 0;   f[7] = 0;
        }
        bfr[j] = f;
    }
    __syncthreads();

    // ---- main loop: prefetched tiles, staggered MFMA/fold ----
    float acc0 = 3.4e38f, acc1 = 3.4e38f, acc2 = 3.4e38f, acc3 = 3.4e38f;
    f32x16 zc = {};
    short8 a = afr[lane];                    // tile 0
#pragma unroll 4
    for (int nt = 0; nt < NT; ++nt) {
        int nn = (nt + 1 < NT) ? nt + 1 : 0;
        short8 an = afr[nn * 64 + lane];     // prefetch next tile
        f32x16 d0 = __builtin_amdgcn_mfma_f32_32x32x16_bf16(a, bfr[0], zc, 0, 0, 0);
        f32x16 d1 = __builtin_amdgcn_mfma_f32_32x32x16_bf16(a, bfr[1], zc, 0, 0, 0);
        acc0 = fold16(acc0, d0);
        f32x16 d2 = __builtin_amdgcn_mfma_f32_32x32x16_bf16(a, bfr[2], zc, 0, 0, 0);
        acc1 = fold16(acc1, d1);
        f32x16 d3 = __builtin_amdgcn_mfma_f32_32x32x16_bf16(a, bfr[3], zc, 0, 0, 0);
        acc2 = fold16(acc2, d2);
        acc3 = fold16(acc3, d3);
        a = an;
    }

    // ---- per-query colmin write (+ry so ref-halves combine by min) ----
    float accs[MPW] = {acc0, acc1, acc2, acc3};
#pragma unroll
    for (int j = 0; j < MPW; ++j) {
        float v = accs[j];
        v = fminf(v, __shfl_xor(v, 32, 64));
        if (half == 0)
            pmin[(size_t)blk * 512 + (wid * 4 + j) * 32 + col] = v + ry[j];
    }
}

// finish: 256 blocks; min-combine ref-halves, sum, one atomicAdd each.
__global__ __launch_bounds__(THREADS)
void finish_kernel(const float* __restrict__ pmin, float* __restrict__ out)
{
    __shared__ float red[THREADS / 64];
    const int tid = threadIdx.x;
    const int c   = blockIdx.x * 2 + (tid >> 7);   // chunk id 0..511
    const int qi  = (tid & 127) * 4;
    const float4 a = *(const float4*)(pmin + (size_t)(c * 2) * 512 + qi);
    const float4 b = *(const float4*)(pmin + (size_t)(c * 2 + 1) * 512 + qi);
    float s = fminf(a.x, b.x) + fminf(a.y, b.y) + fminf(a.z, b.z) + fminf(a.w, b.w);
#pragma unroll
    for (int o = 32; o > 0; o >>= 1) s += __shfl_down(s, o, 64);
    if ((tid & 63) == 0) red[tid >> 6] = s;
    __syncthreads();
    if (tid == 0)
        atomicAdd(out, (red[0] + red[1] + red[2] + red[3]) * (1.0f / 64.0f));
}

extern "C" void kernel_launch(void* const* d_in, const int* in_sizes, int n_in,
                              void* d_out, int out_size, void* d_ws, size_t ws_size,
                              hipStream_t stream) {
    const float* preds = (const float*)d_in[0];
    const float* gts   = (const float*)d_in[1];
    float* out  = (float*)d_out;
    float* pmin = (float*)d_ws;              // 1024*512 floats = 2 MB

    hipMemsetAsync(out, 0, sizeof(float), stream);
    chamfer_kernel<<<NBLK, THREADS, 0, stream>>>(preds, gts, pmin);
    finish_kernel<<<256, THREADS, 0, stream>>>(pmin, out);
}

// Round 10
// 77.371 us; speedup vs baseline: 1.1173x; 1.1173x over previous
//
#include <hip/hip_runtime.h>
#include <hip/hip_bf16.h>

// SeqChamferLoss: B=4, C=3, T=16, N=2048, fp32 in, scalar fp32 out.
// loss = mean over (b,t) of [ sum_m min_n d2 + sum_n min_m d2 ], x=gts, y=preds.
//
// R10 = R9 with the vector-element reference compile fix.
// Symmetric-K fragment design: A-fragment (refs) is the SAME packed 16B for
// both lane halves: pk = [sh0,sh1,sh2,sl0,sl1,sl2,rxh,rxl] (s=-2x, hi/lo bf16
// split, rx=||x||^2). B-fragment: half0=[yh0,yh1,yh2,yh0,yh1,yh2,1,1],
// half1=[yl0,yl1,yl2,yl0,yl1,yl2,0,0]. K-products sum to (sh+sl).(yh+yl)+rx
// = -2x.y + rx exactly (fp32 MFMA accum).
//  - LDS 16B/point -> ALL 2048 refs in 32KB, 4 blocks/CU, no ref-half split
//  - MPW=2 -> fewer live MFMA results
//  - 2 dispatches (chamfer + 1-block finish), no memset

typedef short short8 __attribute__((ext_vector_type(8)));
typedef float f32x16 __attribute__((ext_vector_type(16)));

#define BV 4
#define CV 3
#define TV 16
#define NV 2048
#define PS (TV * NV)
#define THREADS 256
#define NT 64            // all 2048/32 ref tiles
#define MPW 2            // query m-tiles per wave
#define NBLK 1024        // sl(64) x dir(2) x qc(8)

static __device__ inline short bfh(float v) {
    __hip_bfloat16 h = __float2bfloat16(v);
    return *reinterpret_cast<short*>(&h);
}
static __device__ inline float bff(short s) {
    __hip_bfloat16 h;
    *reinterpret_cast<short*>(&h) = s;
    return __bfloat162float(h);
}
static __device__ inline void split2(float v, short& hi, short& lo) {
    short h = bfh(v);
    hi = h;
    lo = bfh(v - bff(h));
}
// verified fold: 16 results + carry, fminf pairs (compiler may fuse min3)
static __device__ inline float fold16(float accv, const f32x16& d) {
    float c0 = fminf(fminf(d[0], d[1]), d[2]);
    c0 = fminf(fminf(c0, d[3]), d[4]);
    c0 = fminf(fminf(c0, d[5]), d[6]);
    float c1 = fminf(fminf(d[7], d[8]), d[9]);
    c1 = fminf(fminf(c1, d[10]), d[11]);
    c1 = fminf(fminf(c1, d[12]), d[13]);
    float c2 = fminf(fminf(accv, d[14]), d[15]);
    return fminf(fminf(c0, c1), c2);
}

__global__ __launch_bounds__(THREADS, 4)
void chamfer_kernel(const float* __restrict__ preds,
                    const float* __restrict__ gts,
                    float* __restrict__ pb)
{
    __shared__ short8 afr[NV];               // 32 KB: 16B per ref point
    __shared__ float red[THREADS / 64];

    const int tid  = threadIdx.x;
    const int lane = tid & 63;
    const int wid  = tid >> 6;
    const int col  = lane & 31;
    const int half = lane >> 5;

    const int blk = blockIdx.x;              // (sl*2 + dir)*8 + qc
    const int qc  = blk & 7;
    const int dir = (blk >> 3) & 1;
    const int sl  = blk >> 4;
    const int b   = sl >> 4, t = sl & 15;

    const size_t base = ((size_t)b * CV * TV + t) * NV;
    const float* rsrc = (dir ? preds : gts) + base;   // refs
    const float* qsrc = (dir ? gts : preds) + base;   // queries

    // ---- stage ALL 2048 refs as packed fragments ----
    // pk = [sh0,sh1,sh2,sl0,sl1,sl2,rxh,rxl]  (16B, same for both K-halves)
#pragma unroll
    for (int i = 0; i < 8; ++i) {
        int p = tid + THREADS * i;
        float x0 = rsrc[p], x1 = rsrc[PS + p], x2 = rsrc[2 * PS + p];
        float rx = fmaf(x0, x0, fmaf(x1, x1, x2 * x2));
        short h0, l0, h1, l1, h2, l2, rh, rl;
        split2(-2.f * x0, h0, l0);
        split2(-2.f * x1, h1, l1);
        split2(-2.f * x2, h2, l2);
        split2(rx, rh, rl);
        short8 pk;
        pk[0] = h0; pk[1] = h1; pk[2] = h2; pk[3] = l0;
        pk[4] = l1; pk[5] = l2; pk[6] = rh; pk[7] = rl;
        afr[p] = pk;
    }

    // ---- B-side (query) fragments in registers ----
    // half0: [yh0,yh1,yh2,yh0,yh1,yh2,1,1]
    // half1: [yl0,yl1,yl2,yl0,yl1,yl2,0,0]
    // K-dot: sh.yh + sl.yh (half0 k3-5 pair with A's sl slots? no --
    //   A is identical across halves: slots [s_h(0:3), s_l(3:6), rx(6:8)];
    //   half0 B = [yh,yh,yh, yh,yh,yh, 1,1] gives sh.yh + sl.yh + rx;
    //   half1 B = [yl,yl,yl, yl,yl,yl, 0,0] gives sh.yl + sl.yl.
    //   Sum over K=16 (both halves contribute to same D column-block rows?)
    // NOTE: 32x32x16 sums ALL 16 K-slots into each D element; lanes 0-31
    // supply k=0..7 and lanes 32-63 supply k=8..15. A must therefore differ
    // per half in general -- but here A's 16B covers k-slots of BOTH halves
    // identically because we feed the same pk to both; the half-0 lanes'
    // B covers yh-terms and half-1 lanes' B covers yl-terms, so total =
    // (sh+sl).(yh+yl) + rx exactly.
    short8 bfr[MPW];
    float  ry[MPW];
    const short ONE = 0x3F80;                // bf16 1.0
#pragma unroll
    for (int j = 0; j < MPW; ++j) {
        int m = qc * 256 + (wid * MPW + j) * 32 + col;
        float y0 = qsrc[m], y1 = qsrc[PS + m], y2 = qsrc[2 * PS + m];
        ry[j] = fmaf(y0, y0, fmaf(y1, y1, y2 * y2));
        short yh0, yl0, yh1, yl1, yh2, yl2;
        split2(y0, yh0, yl0);
        split2(y1, yh1, yl1);
        split2(y2, yh2, yl2);
        short8 f;
        if (half == 0) {
            f[0] = yh0; f[1] = yh1; f[2] = yh2; f[3] = yh0;
            f[4] = yh1; f[5] = yh2; f[6] = ONE; f[7] = ONE;
        } else {
            f[0] = yl0; f[1] = yl1; f[2] = yl2; f[3] = yl0;
            f[4] = yl1; f[5] = yl2; f[6] = 0;   f[7] = 0;
        }
        bfr[j] = f;
    }
    __syncthreads();

    // ---- main loop: 64 ref tiles; packed A read (LDS broadcast) ----
    float acc[MPW] = {3.4e38f, 3.4e38f};
    f32x16 zc = {};
#pragma unroll 4
    for (int nt = 0; nt < NT; ++nt) {
        short8 a = afr[nt * 32 + col];       // both halves read same 16B
#pragma unroll
        for (int j = 0; j < MPW; ++j) {
            f32x16 d = __builtin_amdgcn_mfma_f32_32x32x16_bf16(a, bfr[j], zc, 0, 0, 0);
            acc[j] = fold16(acc[j], d);
        }
    }

    // ---- block reduction: colmin + ry, sum (both halves count -> x2) ----
    float wsum = 0.f;
#pragma unroll
    for (int j = 0; j < MPW; ++j) {
        float v = acc[j];
        v = fminf(v, __shfl_xor(v, 32, 64)); // combine row-halves of the column
        wsum += v + ry[j];
    }
#pragma unroll
    for (int o = 32; o > 0; o >>= 1) wsum += __shfl_down(wsum, o, 64);
    if (lane == 0) red[wid] = wsum;
    __syncthreads();
    if (tid == 0)
        pb[blk] = red[0] + red[1] + red[2] + red[3];
}

// finish: one block sums 1024 partials; scale 0.5 (half-dup) / 64 (mean).
__global__ __launch_bounds__(THREADS)
void finish_kernel(const float* __restrict__ pb, float* __restrict__ out)
{
    __shared__ float red[THREADS / 64];
    const int tid = threadIdx.x;
    const float4 v = *(const float4*)(pb + tid * 4);
    float s = (v.x + v.y) + (v.z + v.w);
#pragma unroll
    for (int o = 32; o > 0; o >>= 1) s += __shfl_down(s, o, 64);
    if ((tid & 63) == 0) red[tid >> 6] = s;
    __syncthreads();
    if (tid == 0)
        out[0] = (red[0] + red[1] + red[2] + red[3]) * (1.0f / 128.0f);
}

extern "C" void kernel_launch(void* const* d_in, const int* in_sizes, int n_in,
                              void* d_out, int out_size, void* d_ws, size_t ws_size,
                              hipStream_t stream) {
    const float* preds = (const float*)d_in[0];
    const float* gts   = (const float*)d_in[1];
    float* out = (float*)d_out;
    float* pb  = (float*)d_ws;               // 1024 floats = 4 KB

    chamfer_kernel<<<NBLK, THREADS, 0, stream>>>(preds, gts, pb);
    finish_kernel<<<1, THREADS, 0, stream>>>(pb, out);
}

// Round 11
// 76.407 us; speedup vs baseline: 1.1314x; 1.0126x over previous
//
#include <hip/hip_runtime.h>
#include <hip/hip_bf16.h>

// SeqChamferLoss: B=4, C=3, T=16, N=2048, fp32 in, scalar fp32 out.
// loss = mean over (b,t) of [ sum_m min_n d2 + sum_n min_m d2 ], x=gts, y=preds.
//
// R11 = R10 (symmetric-K packed fragments, 32KB LDS, 1024 blocks, 4/CU,
// 2 dispatches) with a register-pressure / dependency attack on the main loop:
//  - elementwise f32x16 min-accumulate (16 independent v_min per MFMA, d dies
//    immediately; no per-MFMA depth-3 fold tree) -> keeps MFMA results in
//    VGPRs (no accvgpr round-trip), tree-fold once after the loop
//  - #pragma unroll 2 (bounded live tuples, still 2 ds_reads in flight)

typedef short short8 __attribute__((ext_vector_type(8)));
typedef float f32x16 __attribute__((ext_vector_type(16)));

#define BV 4
#define CV 3
#define TV 16
#define NV 2048
#define PS (TV * NV)
#define THREADS 256
#define NT 64            // all 2048/32 ref tiles
#define MPW 2            // query m-tiles per wave
#define NBLK 1024        // sl(64) x dir(2) x qc(8)

static __device__ inline short bfh(float v) {
    __hip_bfloat16 h = __float2bfloat16(v);
    return *reinterpret_cast<short*>(&h);
}
static __device__ inline float bff(short s) {
    __hip_bfloat16 h;
    *reinterpret_cast<short*>(&h) = s;
    return __bfloat162float(h);
}
static __device__ inline void split2(float v, short& hi, short& lo) {
    short h = bfh(v);
    hi = h;
    lo = bfh(v - bff(h));
}
// elementwise min into the vector accumulator: 16 independent ops
static __device__ inline void vmin16(f32x16& a, const f32x16& d) {
#pragma unroll
    for (int e = 0; e < 16; ++e) a[e] = fminf(a[e], d[e]);
}
// one-time tree reduction of the vector accumulator
static __device__ inline float treemin16(const f32x16& a) {
    float m0 = fminf(fminf(a[0], a[1]), fminf(a[2], a[3]));
    float m1 = fminf(fminf(a[4], a[5]), fminf(a[6], a[7]));
    float m2 = fminf(fminf(a[8], a[9]), fminf(a[10], a[11]));
    float m3 = fminf(fminf(a[12], a[13]), fminf(a[14], a[15]));
    return fminf(fminf(m0, m1), fminf(m2, m3));
}

__global__ __launch_bounds__(THREADS, 4)
void chamfer_kernel(const float* __restrict__ preds,
                    const float* __restrict__ gts,
                    float* __restrict__ pb)
{
    __shared__ short8 afr[NV];               // 32 KB: 16B per ref point
    __shared__ float red[THREADS / 64];

    const int tid  = threadIdx.x;
    const int lane = tid & 63;
    const int wid  = tid >> 6;
    const int col  = lane & 31;
    const int half = lane >> 5;

    const int blk = blockIdx.x;              // (sl*2 + dir)*8 + qc
    const int qc  = blk & 7;
    const int dir = (blk >> 3) & 1;
    const int sl  = blk >> 4;
    const int b   = sl >> 4, t = sl & 15;

    const size_t base = ((size_t)b * CV * TV + t) * NV;
    const float* rsrc = (dir ? preds : gts) + base;   // refs
    const float* qsrc = (dir ? gts : preds) + base;   // queries

    // ---- stage ALL 2048 refs as packed fragments ----
    // pk = [sh0,sh1,sh2,sl0,sl1,sl2,rxh,rxl]  (s=-2x hi/lo split, rx=||x||^2)
#pragma unroll
    for (int i = 0; i < 8; ++i) {
        int p = tid + THREADS * i;
        float x0 = rsrc[p], x1 = rsrc[PS + p], x2 = rsrc[2 * PS + p];
        float rx = fmaf(x0, x0, fmaf(x1, x1, x2 * x2));
        short h0, l0, h1, l1, h2, l2, rh, rl;
        split2(-2.f * x0, h0, l0);
        split2(-2.f * x1, h1, l1);
        split2(-2.f * x2, h2, l2);
        split2(rx, rh, rl);
        short8 pk;
        pk[0] = h0; pk[1] = h1; pk[2] = h2; pk[3] = l0;
        pk[4] = l1; pk[5] = l2; pk[6] = rh; pk[7] = rl;
        afr[p] = pk;
    }

    // ---- B-side (query) fragments ----
    // half0 lanes (k=0..7):  [yh0,yh1,yh2,yh0,yh1,yh2,1,1]
    // half1 lanes (k=8..15): [yl0,yl1,yl2,yl0,yl1,yl2,0,0]
    // A identical in both halves -> sum over K = (sh+sl).(yh+yl) + rx exactly.
    short8 bfr[MPW];
    float  ry[MPW];
    const short ONE = 0x3F80;                // bf16 1.0
#pragma unroll
    for (int j = 0; j < MPW; ++j) {
        int m = qc * 256 + (wid * MPW + j) * 32 + col;
        float y0 = qsrc[m], y1 = qsrc[PS + m], y2 = qsrc[2 * PS + m];
        ry[j] = fmaf(y0, y0, fmaf(y1, y1, y2 * y2));
        short yh0, yl0, yh1, yl1, yh2, yl2;
        split2(y0, yh0, yl0);
        split2(y1, yh1, yl1);
        split2(y2, yh2, yl2);
        short8 f;
        if (half == 0) {
            f[0] = yh0; f[1] = yh1; f[2] = yh2; f[3] = yh0;
            f[4] = yh1; f[5] = yh2; f[6] = ONE; f[7] = ONE;
        } else {
            f[0] = yl0; f[1] = yl1; f[2] = yl2; f[3] = yl0;
            f[4] = yl1; f[5] = yl2; f[6] = 0;   f[7] = 0;
        }
        bfr[j] = f;
    }
    __syncthreads();

    // ---- main loop: elementwise vector-min accumulate, bounded pressure ----
    f32x16 accv0, accv1;
#pragma unroll
    for (int e = 0; e < 16; ++e) { accv0[e] = 3.4e38f; accv1[e] = 3.4e38f; }
    f32x16 zc = {};
#pragma unroll 2
    for (int nt = 0; nt < NT; ++nt) {
        short8 a = afr[nt * 32 + col];       // both halves read same 16B
        f32x16 d0 = __builtin_amdgcn_mfma_f32_32x32x16_bf16(a, bfr[0], zc, 0, 0, 0);
        vmin16(accv0, d0);
        f32x16 d1 = __builtin_amdgcn_mfma_f32_32x32x16_bf16(a, bfr[1], zc, 0, 0, 0);
        vmin16(accv1, d1);
    }

    // ---- one-time tree fold + block reduction ----
    float wsum = 0.f;
    {
        float v = treemin16(accv0);
        v = fminf(v, __shfl_xor(v, 32, 64));
        wsum += v + ry[0];
        v = treemin16(accv1);
        v = fminf(v, __shfl_xor(v, 32, 64));
        wsum += v + ry[1];
    }
#pragma unroll
    for (int o = 32; o > 0; o >>= 1) wsum += __shfl_down(wsum, o, 64);
    if (lane == 0) red[wid] = wsum;
    __syncthreads();
    if (tid == 0)
        pb[blk] = red[0] + red[1] + red[2] + red[3];
}

// finish: one block sums 1024 partials; scale 0.5 (half-dup) / 64 (mean).
__global__ __launch_bounds__(THREADS)
void finish_kernel(const float* __restrict__ pb, float* __restrict__ out)
{
    __shared__ float red[THREADS / 64];
    const int tid = threadIdx.x;
    const float4 v = *(const float4*)(pb + tid * 4);
    float s = (v.x + v.y) + (v.z + v.w);
#pragma unroll
    for (int o = 32; o > 0; o >>= 1) s += __shfl_down(s, o, 64);
    if ((tid & 63) == 0) red[tid >> 6] = s;
    __syncthreads();
    if (tid == 0)
        out[0] = (red[0] + red[1] + red[2] + red[3]) * (1.0f / 128.0f);
}

extern "C" void kernel_launch(void* const* d_in, const int* in_sizes, int n_in,
                              void* d_out, int out_size, void* d_ws, size_t ws_size,
                              hipStream_t stream) {
    const float* preds = (const float*)d_in[0];
    const float* gts   = (const float*)d_in[1];
    float* out = (float*)d_out;
    float* pb  = (float*)d_ws;               // 1024 floats = 4 KB

    chamfer_kernel<<<NBLK, THREADS, 0, stream>>>(preds, gts, pb);
    finish_kernel<<<1, THREADS, 0, stream>>>(pb, out);
}